// Round 3
// baseline (1727.445 us; speedup 1.0000x reference)
//
#include <hip/hip_runtime.h>
#include <hip/hip_cooperative_groups.h>
#include <stdint.h>
#include <math.h>

namespace cg = cooperative_groups;

#define DD 64
#define K_SOURCE_C 100
#define K_MIN_C 50
#define K_MAX_C 1000
#define L_INFL_C 4
#define A_SLOPE_C 1.0
#define COS_EPS_C 1e-8f
#define NBINS 8192
#define CAPC 3584
#define NHB 192
#define NWB 1024   // partials entries (>= max grid of nodewc/fused)
#define GBLK 1024  // fused cooperative grid
#define CAPG 65536 // global candidate buffer for node threshold bin

__device__ __forceinline__ uint32_t f2mono(float f) {
    uint32_t u = __float_as_uint(f);
    return (u & 0x80000000u) ? ~u : (u | 0x80000000u);
}

__constant__ int c_shifts[5] = {51, 38, 25, 12, 0};
__constant__ int c_nbits[5]  = {13, 13, 13, 13, 12};

// ================= fused cooperative kernel =================

struct FusedParams {
    const float *hidden, *scores, *h0, *hidden_q, *alpha_temp, *noise;
    const float *mw1, *mb1, *mw2, *mb2, *rel_embed, *expert_emb, *w_n;
    const int *nodes, *q_rel, *edges, *old_idx, *l_ptr;
    float *cosvals; uint32_t *mx; uint8_t *diff; int *cnt; double *partials;
    int *Kp; int *node_cnt; float *escore, *nscale, *qvec, *qnorm, *wvec;
    uint64_t *T; uint32_t *ghist; uint64_t *gcand; int *gccnt; uint32_t *g_state;
    uint64_t *keys0, *keys1, *nkeys;
    float *out_hidden, *out_scores, *out_h0, *out_L;
    int N, NE, n_old, B, CAP;
};

struct PickScratch4 { uint32_t wtot[4]; int fd; uint32_t fK; uint32_t total; };

// block-wide descending-bin pick, 256 threads
__device__ void block_pick256(const uint32_t* hist, int nbins, uint32_t Kr, PickScratch4* sc) {
    int t = threadIdx.x;
    int PB = nbins >> 8;                  // 32 (13-bit) or 16 (12-bit)
    int lane = t & 63, wid = t >> 6;
    uint32_t csum = 0;
    for (int j = 0; j < PB; j++) csum += hist[PB * t + j];
    uint32_t ssum = csum;                 // inclusive suffix within wave (desc. idx)
    for (int off = 1; off < 64; off <<= 1) {
        uint32_t v = __shfl_down(ssum, off, 64);
        if (lane + off < 64) ssum += v;
    }
    if (lane == 0) sc->wtot[wid] = ssum;
    if (t == 0) sc->fd = -1;
    __syncthreads();
    uint32_t above = 0, total = 0;
    for (int w = 0; w < 4; w++) {
        uint32_t v = sc->wtot[w];
        total += v;
        if (w > wid) above += v;
    }
    uint32_t gcnt = ssum + above - csum;  // strictly above this thread's chunk
    int fd = -1; uint32_t fK = 0;
    for (int j = PB - 1; j >= 0; j--) {
        uint32_t h = hist[PB * t + j];
        if (h && gcnt < Kr && gcnt + h >= Kr) { fd = PB * t + j; fK = Kr - gcnt; }
        gcnt += h;
    }
    if (fd >= 0) { sc->fd = fd; sc->fK = fK; }
    if (t == 0) sc->total = total;
    __syncthreads();
}

union ShMem {
    uint32_t hist[NBINS];                              // 32 KB
    struct { float cin[2 * DD]; float h1s[DD]; } ctx;
    double red[4][4];
    struct { int lcnt[64]; int lbase[64]; } cp;
};

__global__ __launch_bounds__(256, 4)
void fused_kernel(FusedParams p) {
    cg::grid_group grid = cg::this_grid();
    __shared__ ShMem sh;
    __shared__ PickScratch4 sc;
    __shared__ int s_nloc[2];
    int t = threadIdx.x, blk = blockIdx.x, G = gridDim.x;

    // ---- P0: zero state + K(l) + ctx MLP (blocks < B) ----
    for (int i = blk * 256 + t; i < p.N; i += G * 256) { p.mx[i] = 0u; p.diff[i] = 1; }
    for (int i = blk * 256 + t; i < NBINS; i += G * 256) p.ghist[i] = 0u;
    if (blk == 0 && t < p.B) p.cnt[t] = 0;
    if (blk == 0 && t == 0) {
        *p.node_cnt = 0; *p.gccnt = 0;
        double l = (double)(*p.l_ptr);
        int K;
        if (l < (double)L_INFL_C) {
            double s = 1.0 / (1.0 + exp(-A_SLOPE_C * (l - L_INFL_C / 2.0)));
            K = (int)(K_SOURCE_C + (K_MAX_C - K_SOURCE_C) * s);
        } else {
            double s = 1.0 / (1.0 + exp(-A_SLOPE_C * (l - 3.0 * L_INFL_C / 2.0)));
            K = (int)(K_MIN_C + (K_MAX_C - K_MIN_C) * (1.0 - s));
        }
        *p.Kp = K;
    }
    if (blk < p.B) {
        int b = blk;
        float qv = 0.f;
        if (t < DD) {
            int q = p.q_rel[b];
            qv = p.rel_embed[(size_t)q * DD + t];
            p.qvec[b * DD + t] = qv;
            sh.ctx.cin[t] = p.hidden_q[b * DD + t];
            sh.ctx.cin[DD + t] = qv;
        }
        __syncthreads();
        if (t < DD) {
            float acc = p.mb1[t];
            for (int j = 0; j < 2 * DD; j++) acc += sh.ctx.cin[j] * p.mw1[j * DD + t];
            sh.ctx.h1s[t] = fmaxf(acc, 0.f);
        }
        __syncthreads();
        if (t < DD) {
            float c = p.mb2[t];
            for (int j = 0; j < DD; j++) c += sh.ctx.h1s[j] * p.mw2[j * DD + t];
            float e0 = c * p.expert_emb[0 * DD + t];
            float e1 = c * p.expert_emb[1 * DD + t];
            float e2 = c * p.expert_emb[2 * DD + t];
            float wn = c * p.w_n[t];
            float qq = qv * qv;
            for (int m = 32; m >= 1; m >>= 1) {
                e0 += __shfl_xor(e0, m); e1 += __shfl_xor(e1, m); e2 += __shfl_xor(e2, m);
                wn += __shfl_xor(wn, m); qq += __shfl_xor(qq, m);
            }
            if (t == 0) {
                p.escore[b * 3 + 0] = e0; p.escore[b * 3 + 1] = e1; p.escore[b * 3 + 2] = e2;
                p.nscale[b] = fmaxf(wn, 0.f) + log1pf(expf(-fabsf(wn)));
                p.qnorm[b] = fmaxf(sqrtf(qq), COS_EPS_C);
            }
        }
    }
    grid.sync();

    // ---- P1: diff clears + segment max ----
    for (int j = blk * 256 + t; j < p.n_old; j += G * 256) {
        int idx = p.old_idx[j];
        if (idx >= 0 && idx < p.N) p.diff[idx] = 0;
    }
    for (int e = blk * 256 + t; e < p.NE; e += G * 256) {
        int o = p.edges[(size_t)e * 6 + 5];
        if (o >= 0 && o < p.N) atomicMax(&p.mx[o], f2mono(p.alpha_temp[e]));
    }
    grid.sync();

    // ---- P2: cosine + expert-weight partial sums (register acc, no hot atomics) ----
    {
        int sub = t & 15;
        double s0 = 0, s1 = 0, s2 = 0, sq = 0;
        int ngroups = (p.N + 15) >> 4;
        for (int g = blk; g < ngroups; g += G) {
            int node = g * 16 + (t >> 4);
            if (node < p.N) {
                int b = p.nodes[2 * node];
                bool bv = (b >= 0 && b < p.B);
                float4 h4 = *(const float4*)(p.hidden + (size_t)node * DD + sub * 4);
                float num = 0.f;
                if (bv) {
                    float4 q4 = *(const float4*)(p.qvec + b * DD + sub * 4);
                    num = h4.x * q4.x + h4.y * q4.y + h4.z * q4.z + h4.w * q4.w;
                }
                float hs = h4.x * h4.x + h4.y * h4.y + h4.z * h4.z + h4.w * h4.w;
                for (int m = 8; m >= 1; m >>= 1) { num += __shfl_xor(num, m); hs += __shfl_xor(hs, m); }
                if (sub == 0) {
                    float qn = bv ? p.qnorm[b] : COS_EPS_C;
                    p.cosvals[node] = num / (fmaxf(sqrtf(hs), COS_EPS_C) * qn);
                    if (bv) {
                        float ns = p.nscale[b];
                        float e0 = p.escore[b * 3 + 0] + p.noise[3 * node + 0] * ns;
                        float e1 = p.escore[b * 3 + 1] + p.noise[3 * node + 1] * ns;
                        float e2 = p.escore[b * 3 + 2] + p.noise[3 * node + 2] * ns;
                        float mm = fmaxf(e0, fmaxf(e1, e2));
                        float x0 = expf(e0 - mm), x1 = expf(e1 - mm), x2 = expf(e2 - mm);
                        float s = x0 + x1 + x2;
                        x0 /= s; x1 /= s; x2 /= s;
                        s0 += x0; s1 += x1; s2 += x2;
                        sq += (double)x0 * x0 + (double)x1 * x1 + (double)x2 * x2;
                    }
                }
            }
        }
        for (int m = 32; m >= 1; m >>= 1) {
            s0 += __shfl_xor(s0, m); s1 += __shfl_xor(s1, m);
            s2 += __shfl_xor(s2, m); sq += __shfl_xor(sq, m);
        }
        int wid = t >> 6, lane = t & 63;
        if (lane == 0) { sh.red[wid][0] = s0; sh.red[wid][1] = s1; sh.red[wid][2] = s2; sh.red[wid][3] = sq; }
        __syncthreads();
        if (t == 0) {
            double a0 = 0, a1 = 0, a2 = 0, a3 = 0;
            for (int w = 0; w < 4; w++) { a0 += sh.red[w][0]; a1 += sh.red[w][1]; a2 += sh.red[w][2]; a3 += sh.red[w][3]; }
            p.partials[blk * 4 + 0] = a0; p.partials[blk * 4 + 1] = a1;
            p.partials[blk * 4 + 2] = a2; p.partials[blk * 4 + 3] = a3;
        }
    }
    grid.sync();

    // ---- P3: compact per-row keys + node keys ----
    for (int i0 = blk * 256; i0 < p.N; i0 += G * 256) {
        if (t < p.B) sh.cp.lcnt[t] = 0;
        if (t == 0) s_nloc[0] = 0;
        __syncthreads();
        int i = i0 + t;
        int b = -1, loc = 0, nl = 0;
        bool isdiff = (i < p.N) && p.diff[i];
        if (isdiff) {
            nl = atomicAdd(&s_nloc[0], 1);
            int bb = p.nodes[2 * i];
            if (bb >= 0 && bb < p.B) { b = bb; loc = atomicAdd(&sh.cp.lcnt[b], 1); }
        }
        __syncthreads();
        if (t < p.B) sh.cp.lbase[t] = sh.cp.lcnt[t] ? atomicAdd(&p.cnt[t], sh.cp.lcnt[t]) : 0;
        if (t == 0) s_nloc[1] = s_nloc[0] ? atomicAdd(p.node_cnt, s_nloc[0]) : 0;
        __syncthreads();
        if (isdiff) {
            p.nkeys[s_nloc[1] + nl] = ((uint64_t)p.mx[i] << 32) | (uint64_t)(0xFFFFFFFFu - (uint32_t)i);
            if (b >= 0) {
                int pos = sh.cp.lbase[b] + loc;
                if (pos < p.CAP) {
                    int ei = p.nodes[2 * i + 1];
                    uint64_t tb = (uint64_t)(0xFFFFFFFFu - (uint32_t)ei);
                    p.keys0[(size_t)b * p.CAP + pos] = ((uint64_t)f2mono(p.scores[i]) << 32) | tb;
                    p.keys1[(size_t)b * p.CAP + pos] = ((uint64_t)f2mono(p.cosvals[i]) << 32) | tb;
                }
            }
        }
        __syncthreads();
    }
    grid.sync();

    // ---- P4: row selections (blocks 0..2B-1) + node level-0 histogram ----
    if (blk < 2 * p.B) {
        int row = (blk < p.B) ? blk : blk - p.B;
        const uint64_t* list = ((blk < p.B) ? p.keys0 : p.keys1) + (size_t)row * p.CAP;
        int n = min(p.cnt[row], p.CAP);
        int K = *p.Kp;
        if (n <= K) {
            if (t == 0) p.T[blk] = 0ull;
        } else {
            uint64_t pref = 0ull; uint32_t Kr = (uint32_t)K; bool ok = true;
            for (int lev = 0; lev < 5 && ok; lev++) {
                int nb2 = 1 << c_nbits[lev];
                for (int j = t; j < nb2; j += 256) sh.hist[j] = 0;
                __syncthreads();
                uint64_t pmask = (lev == 0) ? 0ull : (~0ull << c_shifts[lev - 1]);
                int shf = c_shifts[lev];
                uint32_t bmask = (uint32_t)(nb2 - 1);
                for (int i = t; i < n; i += 256) {
                    uint64_t key = list[i];
                    if ((key & pmask) == pref)
                        atomicAdd(&sh.hist[(uint32_t)(key >> shf) & bmask], 1u);
                }
                __syncthreads();
                block_pick256(sh.hist, nb2, Kr, &sc);
                if (sc.fd < 0) ok = false;
                else { pref |= ((uint64_t)sc.fd) << shf; Kr = sc.fK; }
                __syncthreads();
            }
            if (t == 0) p.T[blk] = ok ? pref : 0ull;
        }
    } else {
        for (int j = t; j < NBINS; j += 256) sh.hist[j] = 0;
        __syncthreads();
        int n = *p.node_cnt;
        int base = (blk - 2 * p.B) * 256 + t;
        int stride = (G - 2 * p.B) * 256;
        for (int i = base; i < n; i += stride)
            atomicAdd(&sh.hist[(uint32_t)(p.nkeys[i] >> 51)], 1u);
        __syncthreads();
        for (int j = t; j < NBINS; j += 256) {
            uint32_t v = sh.hist[j];
            if (v) atomicAdd(&p.ghist[j], v);
        }
    }
    grid.sync();

    // ---- P5: node level-0 pick + stats (block 0) ----
    if (blk == 0) {
        int K = *p.Kp;
        block_pick256(p.ghist, NBINS, (uint32_t)K, &sc);
        if (t == 0) {
            if (sc.total <= (uint32_t)K || sc.fd < 0) { p.T[2 * p.B] = 0ull; p.g_state[0] = 0xFFFFFFFFu; }
            else { p.g_state[0] = (uint32_t)sc.fd; p.g_state[1] = sc.fK; }
        }
        double s0 = 0, s1 = 0, s2 = 0, sq = 0;
        for (int i = t; i < G; i += 256) {
            s0 += p.partials[4 * i + 0]; s1 += p.partials[4 * i + 1];
            s2 += p.partials[4 * i + 2]; sq += p.partials[4 * i + 3];
        }
        for (int m = 32; m >= 1; m >>= 1) {
            s0 += __shfl_xor(s0, m); s1 += __shfl_xor(s1, m);
            s2 += __shfl_xor(s2, m); sq += __shfl_xor(sq, m);
        }
        int wid = t >> 6, lane = t & 63;
        __syncthreads();   // hist (union) no longer needed; reuse as red
        if (lane == 0) { sh.red[wid][0] = s0; sh.red[wid][1] = s1; sh.red[wid][2] = s2; sh.red[wid][3] = sq; }
        __syncthreads();
        if (t == 0) {
            double c0 = 0, c1 = 0, c2 = 0, S2 = 0;
            for (int w = 0; w < 4; w++) { c0 += sh.red[w][0]; c1 += sh.red[w][1]; c2 += sh.red[w][2]; S2 += sh.red[w][3]; }
            double tot = c0 + c1 + c2;
            p.wvec[0] = (float)(c0 / tot); p.wvec[1] = (float)(c1 / tot); p.wvec[2] = (float)(c2 / tot);
            double n = 3.0 * (double)p.N;
            double mean = tot / n;
            double var = (S2 - tot * tot / n) / (n - 1.0);
            if (var < 0) var = 0;
            double cv = sqrt(var) / (mean + 1e-5);
            *p.out_L = (float)(cv * cv);
        }
    }
    grid.sync();

    // ---- P6: grid-parallel collect of node threshold-bin candidates ----
    {
        uint32_t fd0 = p.g_state[0];
        if (fd0 != 0xFFFFFFFFu) {
            int n = *p.node_cnt;
            for (int i = blk * 256 + t; i < n; i += G * 256) {
                uint64_t key = p.nkeys[i];
                if ((uint32_t)(key >> 51) == fd0) {
                    int pos = atomicAdd(p.gccnt, 1);
                    if (pos < CAPG) p.gcand[pos] = key;
                }
            }
        }
    }
    grid.sync();

    // ---- P7: finish node select over candidates (block 0) ----
    if (blk == 0) {
        uint32_t fd0 = p.g_state[0];
        if (fd0 != 0xFFFFFFFFu) {
            int tot = *p.gccnt;
            const uint64_t* src = p.gcand;
            int mm = tot;
            if (tot > CAPG) { src = p.nkeys; mm = *p.node_cnt; }   // overflow fallback
            uint64_t pref = ((uint64_t)fd0) << 51;
            uint32_t Kr = p.g_state[1];
            bool ok = true;
            for (int lev = 1; lev < 5 && ok; lev++) {
                int nb2 = 1 << c_nbits[lev];
                for (int j = t; j < nb2; j += 256) sh.hist[j] = 0;
                __syncthreads();
                uint64_t pmask = ~0ull << c_shifts[lev - 1];
                int shf = c_shifts[lev];
                uint32_t bmask = (uint32_t)(nb2 - 1);
                for (int i = t; i < mm; i += 256) {
                    uint64_t key = src[i];
                    if ((key & pmask) == pref)
                        atomicAdd(&sh.hist[(uint32_t)(key >> shf) & bmask], 1u);
                }
                __syncthreads();
                block_pick256(sh.hist, nb2, Kr, &sc);
                if (sc.fd < 0) ok = false;
                else { pref |= ((uint64_t)sc.fd) << shf; Kr = sc.fK; }
                __syncthreads();
            }
            if (t == 0) p.T[2 * p.B] = ok ? pref : 0ull;
        }
    }
    grid.sync();

    // ---- P8: fused epilogue ----
    {
        float w0 = p.wvec[0], w1 = p.wvec[1], w2 = p.wvec[2];
        int sub = t & 15;
        int ngroups = (p.N + 15) >> 4;
        for (int g = blk; g < ngroups; g += G) {
            int node = g * 16 + (t >> 4);
            if (node < p.N) {
                float wm;
                if (!p.diff[node]) {
                    wm = w0 + w1 + w2;
                } else {
                    int b = p.nodes[2 * node];
                    int ei = p.nodes[2 * node + 1];
                    float m0 = 0.f, m1 = 0.f;
                    if (b >= 0 && b < p.B) {
                        uint64_t tb = (uint64_t)(0xFFFFFFFFu - (uint32_t)ei);
                        uint64_t k0 = ((uint64_t)f2mono(p.scores[node]) << 32) | tb;
                        uint64_t k1 = ((uint64_t)f2mono(p.cosvals[node]) << 32) | tb;
                        m0 = (k0 >= p.T[b]) ? 1.f : 0.f;
                        m1 = (k1 >= p.T[p.B + b]) ? 1.f : 0.f;
                    }
                    uint64_t k2 = ((uint64_t)p.mx[node] << 32) | (uint64_t)(0xFFFFFFFFu - (uint32_t)node);
                    float m2 = (k2 >= p.T[2 * p.B]) ? 1.f : 0.f;
                    wm = w0 * m0 + w1 * m1 + w2 * m2;
                }
                size_t off = (size_t)node * DD + sub * 4;
                float4 h4 = *(const float4*)(p.hidden + off);
                float4 g4 = *(const float4*)(p.h0 + off);
                float4 o1, o2;
                o1.x = h4.x * wm; o1.y = h4.y * wm; o1.z = h4.z * wm; o1.w = h4.w * wm;
                o2.x = g4.x * wm; o2.y = g4.y * wm; o2.z = g4.z * wm; o2.w = g4.w * wm;
                *(float4*)(p.out_hidden + off) = o1;
                *(float4*)(p.out_h0 + off) = o2;
                if (sub == 0) p.out_scores[node] = p.scores[node] * wm;
            }
        }
    }
}

// ================= fallback pipeline (round-2, unchanged) =================

__global__ void init_kernel(uint32_t* mx, uint8_t* diff, int* cnt,
                            int* Kp, int* node_cnt, uint32_t* ghist,
                            const int* l_ptr, int N, int B) {
    int i = blockIdx.x * blockDim.x + threadIdx.x;
    if (i < N) { mx[i] = 0u; diff[i] = 1; }
    if (i < B) cnt[i] = 0;
    if (i < NBINS) ghist[i] = 0u;
    if (i == 0) {
        *node_cnt = 0;
        double l = (double)(*l_ptr);
        int K;
        if (l < (double)L_INFL_C) {
            double s = 1.0 / (1.0 + exp(-A_SLOPE_C * (l - L_INFL_C / 2.0)));
            K = (int)(K_SOURCE_C + (K_MAX_C - K_SOURCE_C) * s);
        } else {
            double s = 1.0 / (1.0 + exp(-A_SLOPE_C * (l - 3.0 * L_INFL_C / 2.0)));
            K = (int)(K_MIN_C + (K_MAX_C - K_MIN_C) * (1.0 - s));
        }
        *Kp = K;
    }
}

__global__ void diff_kernel(uint8_t* diff, const int* old_idx, int n_old, int N) {
    int j = blockIdx.x * blockDim.x + threadIdx.x;
    if (j < n_old) { int idx = old_idx[j]; if (idx >= 0 && idx < N) diff[idx] = 0; }
}

__global__ void ctx_kernel(const float* hidden_q, const int* q_rel, const float* rel_embed,
                           const float* w1, const float* b1, const float* w2, const float* b2,
                           const float* expert_emb, const float* w_n,
                           float* escore, float* nscale, float* qvec, float* qnorm, int B) {
    int b = blockIdx.x, t = threadIdx.x;
    __shared__ float cin[2 * DD];
    __shared__ float h1s[DD];
    int q = q_rel[b];
    float qv = rel_embed[(size_t)q * DD + t];
    qvec[b * DD + t] = qv;
    cin[t] = hidden_q[b * DD + t];
    cin[DD + t] = qv;
    __syncthreads();
    float acc = b1[t];
    for (int j = 0; j < 2 * DD; j++) acc += cin[j] * w1[j * DD + t];
    h1s[t] = fmaxf(acc, 0.f);
    __syncthreads();
    float c = b2[t];
    for (int j = 0; j < DD; j++) c += h1s[j] * w2[j * DD + t];
    float e0 = c * expert_emb[0 * DD + t];
    float e1 = c * expert_emb[1 * DD + t];
    float e2 = c * expert_emb[2 * DD + t];
    float wn = c * w_n[t];
    float qq = qv * qv;
    for (int m = 32; m >= 1; m >>= 1) {
        e0 += __shfl_xor(e0, m); e1 += __shfl_xor(e1, m); e2 += __shfl_xor(e2, m);
        wn += __shfl_xor(wn, m); qq += __shfl_xor(qq, m);
    }
    if (t == 0) {
        escore[b * 3 + 0] = e0; escore[b * 3 + 1] = e1; escore[b * 3 + 2] = e2;
        nscale[b] = fmaxf(wn, 0.f) + log1pf(expf(-fabsf(wn)));
        qnorm[b] = fmaxf(sqrtf(qq), COS_EPS_C);
    }
}

__global__ void segmax_kernel(const int* edges, const float* alpha_temp, uint32_t* mx,
                              int NE, int N) {
    int e = blockIdx.x * blockDim.x + threadIdx.x;
    if (e < NE) {
        int o = edges[(size_t)e * 6 + 5];
        if (o >= 0 && o < N) atomicMax(&mx[o], f2mono(alpha_temp[e]));
    }
}

__global__ void nodewc_kernel(const float* hidden, const int* nodes, const float* noise,
                              const float* qvec, const float* qnorm,
                              const float* escore, const float* nscale,
                              float* cosvals, double* partials, int N, int B) {
    int t = threadIdx.x;
    int sub = t & 15;
    double s0 = 0, s1 = 0, s2 = 0, sq = 0;
    int ngroups = (N + 15) >> 4;
    for (int g = blockIdx.x; g < ngroups; g += gridDim.x) {
        int node = g * 16 + (t >> 4);
        if (node < N) {
            int b = nodes[2 * node];
            bool bv = (b >= 0 && b < B);
            float4 h4 = *(const float4*)(hidden + (size_t)node * DD + sub * 4);
            float num = 0.f;
            if (bv) {
                float4 q4 = *(const float4*)(qvec + b * DD + sub * 4);
                num = h4.x * q4.x + h4.y * q4.y + h4.z * q4.z + h4.w * q4.w;
            }
            float hs = h4.x * h4.x + h4.y * h4.y + h4.z * h4.z + h4.w * h4.w;
            for (int m = 8; m >= 1; m >>= 1) { num += __shfl_xor(num, m); hs += __shfl_xor(hs, m); }
            if (sub == 0) {
                float qn = bv ? qnorm[b] : COS_EPS_C;
                cosvals[node] = num / (fmaxf(sqrtf(hs), COS_EPS_C) * qn);
                if (bv) {
                    float ns = nscale[b];
                    float e0 = escore[b * 3 + 0] + noise[3 * node + 0] * ns;
                    float e1 = escore[b * 3 + 1] + noise[3 * node + 1] * ns;
                    float e2 = escore[b * 3 + 2] + noise[3 * node + 2] * ns;
                    float mm = fmaxf(e0, fmaxf(e1, e2));
                    float x0 = expf(e0 - mm), x1 = expf(e1 - mm), x2 = expf(e2 - mm);
                    float s = x0 + x1 + x2;
                    x0 /= s; x1 /= s; x2 /= s;
                    s0 += x0; s1 += x1; s2 += x2;
                    sq += (double)x0 * x0 + (double)x1 * x1 + (double)x2 * x2;
                }
            }
        }
    }
    for (int m = 32; m >= 1; m >>= 1) {
        s0 += __shfl_xor(s0, m); s1 += __shfl_xor(s1, m);
        s2 += __shfl_xor(s2, m); sq += __shfl_xor(sq, m);
    }
    __shared__ double red[4][4];
    int wid = t >> 6, lane = t & 63;
    if (lane == 0) { red[wid][0] = s0; red[wid][1] = s1; red[wid][2] = s2; red[wid][3] = sq; }
    __syncthreads();
    if (t == 0) {
        double a0 = 0, a1 = 0, a2 = 0, a3 = 0;
        for (int w = 0; w < 4; w++) { a0 += red[w][0]; a1 += red[w][1]; a2 += red[w][2]; a3 += red[w][3]; }
        partials[blockIdx.x * 4 + 0] = a0;
        partials[blockIdx.x * 4 + 1] = a1;
        partials[blockIdx.x * 4 + 2] = a2;
        partials[blockIdx.x * 4 + 3] = a3;
    }
}

__global__ void stats_kernel(const double* partials, float* wvec, float* out_L, int N) {
    int t = threadIdx.x;
    double s0 = 0, s1 = 0, s2 = 0, sq = 0;
    for (int i = t; i < NWB; i += 256) {
        s0 += partials[4 * i + 0]; s1 += partials[4 * i + 1];
        s2 += partials[4 * i + 2]; sq += partials[4 * i + 3];
    }
    for (int m = 32; m >= 1; m >>= 1) {
        s0 += __shfl_xor(s0, m); s1 += __shfl_xor(s1, m);
        s2 += __shfl_xor(s2, m); sq += __shfl_xor(sq, m);
    }
    __shared__ double red[4][4];
    int wid = t >> 6, lane = t & 63;
    if (lane == 0) { red[wid][0] = s0; red[wid][1] = s1; red[wid][2] = s2; red[wid][3] = sq; }
    __syncthreads();
    if (t == 0) {
        double c0 = 0, c1 = 0, c2 = 0, S2 = 0;
        for (int w = 0; w < 4; w++) { c0 += red[w][0]; c1 += red[w][1]; c2 += red[w][2]; S2 += red[w][3]; }
        double tot = c0 + c1 + c2;
        wvec[0] = (float)(c0 / tot); wvec[1] = (float)(c1 / tot); wvec[2] = (float)(c2 / tot);
        double n = 3.0 * (double)N;
        double mean = tot / n;
        double var = (S2 - tot * tot / n) / (n - 1.0);
        if (var < 0) var = 0;
        double cv = sqrt(var) / (mean + 1e-5);
        *out_L = (float)(cv * cv);
    }
}

__global__ void compact_kernel(const int* nodes, const uint8_t* diff, const float* scores,
                               const float* cosvals, const uint32_t* mx,
                               uint64_t* keys0, uint64_t* keys1, uint64_t* nkeys,
                               int* cnt, int* node_cnt, int N, int B, int CAP) {
    __shared__ int lcnt[64];
    __shared__ int lbase[64];
    __shared__ int nloc_cnt, nloc_base;
    int t = threadIdx.x;
    if (t < B) lcnt[t] = 0;
    if (t == 0) nloc_cnt = 0;
    __syncthreads();
    int i = blockIdx.x * blockDim.x + t;
    int b = -1, loc = 0, nl = 0;
    bool isdiff = (i < N) && diff[i];
    if (isdiff) {
        nl = atomicAdd(&nloc_cnt, 1);
        int bb = nodes[2 * i];
        if (bb >= 0 && bb < B) { b = bb; loc = atomicAdd(&lcnt[b], 1); }
    }
    __syncthreads();
    if (t < B) lbase[t] = lcnt[t] ? atomicAdd(&cnt[t], lcnt[t]) : 0;
    if (t == 0) nloc_base = nloc_cnt ? atomicAdd(node_cnt, nloc_cnt) : 0;
    __syncthreads();
    if (isdiff) {
        nkeys[nloc_base + nl] = ((uint64_t)mx[i] << 32) | (uint64_t)(0xFFFFFFFFu - (uint32_t)i);
        if (b >= 0) {
            int pos = lbase[b] + loc;
            if (pos < CAP) {
                int ei = nodes[2 * i + 1];
                uint64_t tb = (uint64_t)(0xFFFFFFFFu - (uint32_t)ei);
                keys0[(size_t)b * CAP + pos] = ((uint64_t)f2mono(scores[i]) << 32) | tb;
                keys1[(size_t)b * CAP + pos] = ((uint64_t)f2mono(cosvals[i]) << 32) | tb;
            }
        }
    }
}

struct PickScratch { uint32_t wtot[16]; int fd; uint32_t fK; uint32_t total; };

__device__ void block_pick(const uint32_t* hist, int nbins, uint32_t Kr, PickScratch* sc) {
    int t = threadIdx.x;
    int PB = nbins >> 10;
    int lane = t & 63, wid = t >> 6;
    uint32_t csum = 0;
    for (int j = 0; j < PB; j++) csum += hist[PB * t + j];
    uint32_t ssum = csum;
    for (int off = 1; off < 64; off <<= 1) {
        uint32_t v = __shfl_down(ssum, off, 64);
        if (lane + off < 64) ssum += v;
    }
    if (lane == 0) sc->wtot[wid] = ssum;
    if (t == 0) sc->fd = -1;
    __syncthreads();
    uint32_t above = 0, total = 0;
    for (int w = 0; w < 16; w++) {
        uint32_t v = sc->wtot[w];
        total += v;
        if (w > wid) above += v;
    }
    uint32_t gcnt = ssum + above - csum;
    int fd = -1; uint32_t fK = 0;
    for (int j = PB - 1; j >= 0; j--) {
        uint32_t h = hist[PB * t + j];
        if (h && gcnt < Kr && gcnt + h >= Kr) { fd = PB * t + j; fK = Kr - gcnt; }
        gcnt += h;
    }
    if (fd >= 0) { sc->fd = fd; sc->fK = fK; }
    if (t == 0) sc->total = total;
    __syncthreads();
}

__global__ __launch_bounds__(1024)
void selA_kernel(const uint64_t* keys0, const uint64_t* keys1, const int* cnt,
                 const uint64_t* nkeys, const int* node_cnt, uint32_t* ghist,
                 uint64_t* T, const int* Kp, int B, int CAP) {
    __shared__ uint32_t hist[NBINS];
    __shared__ PickScratch sc;
    int t = threadIdx.x;
    int blk = blockIdx.x;
    if (blk < 2 * B) {
        int row = (blk < B) ? blk : blk - B;
        const uint64_t* list = ((blk < B) ? keys0 : keys1) + (size_t)row * CAP;
        int n = min(cnt[row], CAP);
        int K = *Kp;
        if (n <= K) { if (t == 0) T[blk] = 0ull; return; }
        uint64_t pref = 0ull;
        uint32_t Kr = (uint32_t)K;
        for (int lev = 0; lev < 5; lev++) {
            int nb = 1 << c_nbits[lev];
            for (int j = t; j < nb; j += 1024) hist[j] = 0;
            __syncthreads();
            uint64_t pmask = (lev == 0) ? 0ull : (~0ull << c_shifts[lev - 1]);
            int sh = c_shifts[lev];
            uint32_t bmask = (uint32_t)(nb - 1);
            for (int i = t; i < n; i += 1024) {
                uint64_t key = list[i];
                if ((key & pmask) == pref)
                    atomicAdd(&hist[(uint32_t)(key >> sh) & bmask], 1u);
            }
            __syncthreads();
            block_pick(hist, nb, Kr, &sc);
            if (sc.fd < 0) { if (t == 0) T[blk] = 0ull; return; }
            pref |= ((uint64_t)sc.fd) << sh;
            Kr = sc.fK;
            __syncthreads();
        }
        if (t == 0) T[blk] = pref;
    } else {
        int nb = blk - 2 * B;
        for (int j = t; j < NBINS; j += 1024) hist[j] = 0;
        __syncthreads();
        int n = *node_cnt;
        for (int i = nb * 1024 + t; i < n; i += NHB * 1024)
            atomicAdd(&hist[(uint32_t)(nkeys[i] >> 51)], 1u);
        __syncthreads();
        for (int j = t; j < NBINS; j += 1024) {
            uint32_t v = hist[j];
            if (v) atomicAdd(&ghist[j], v);
        }
    }
}

__global__ __launch_bounds__(1024)
void selB_kernel(const uint64_t* nkeys, const int* node_cnt, const uint32_t* ghist,
                 uint64_t* T, const int* Kp, int B) {
    __shared__ uint32_t hist[NBINS];
    __shared__ uint64_t cand[CAPC];
    __shared__ PickScratch sc;
    __shared__ int ccnt;
    int t = threadIdx.x;
    int K = *Kp;
    int n = *node_cnt;
    for (int j = t; j < NBINS; j += 1024) hist[j] = ghist[j];
    __syncthreads();
    block_pick(hist, NBINS, (uint32_t)K, &sc);
    if (sc.total <= (uint32_t)K || sc.fd < 0) { if (t == 0) T[2 * B] = 0ull; return; }
    int fd0 = sc.fd;
    uint64_t pref = ((uint64_t)fd0) << 51;
    uint32_t Kr = sc.fK;
    if (t == 0) ccnt = 0;
    __syncthreads();
    for (int i = t; i < n; i += 1024) {
        uint64_t key = nkeys[i];
        if ((int)(key >> 51) == fd0) {
            int p = atomicAdd(&ccnt, 1);
            if (p < CAPC) cand[p] = key;
        }
    }
    __syncthreads();
    int m = ccnt;
    bool inlds = (m <= CAPC);
    if (!inlds) m = n;
    for (int lev = 1; lev < 5; lev++) {
        int nb = 1 << c_nbits[lev];
        for (int j = t; j < nb; j += 1024) hist[j] = 0;
        __syncthreads();
        uint64_t pmask = ~0ull << c_shifts[lev - 1];
        int sh = c_shifts[lev];
        uint32_t bmask = (uint32_t)(nb - 1);
        for (int i = t; i < m; i += 1024) {
            uint64_t key = inlds ? cand[i] : nkeys[i];
            if ((key & pmask) == pref)
                atomicAdd(&hist[(uint32_t)(key >> sh) & bmask], 1u);
        }
        __syncthreads();
        block_pick(hist, nb, Kr, &sc);
        if (sc.fd < 0) { if (t == 0) T[2 * B] = 0ull; return; }
        pref |= ((uint64_t)sc.fd) << sh;
        Kr = sc.fK;
        __syncthreads();
    }
    if (t == 0) T[2 * B] = pref;
}

__global__ void final_kernel(const float* hidden, const float* h0, const float* scores,
                             const int* nodes, const uint8_t* diff, const float* cosvals,
                             const uint32_t* mx, const uint64_t* T, const float* wvec,
                             float* out_hidden, float* out_scores, float* out_h0,
                             int N, int B) {
    int t = threadIdx.x;
    int node = blockIdx.x * 16 + (t >> 4);
    int sub = t & 15;
    if (node >= N) return;
    float w0 = wvec[0], w1 = wvec[1], w2 = wvec[2];
    float wm;
    if (!diff[node]) {
        wm = w0 + w1 + w2;
    } else {
        int b = nodes[2 * node];
        int ei = nodes[2 * node + 1];
        float m0 = 0.f, m1 = 0.f;
        if (b >= 0 && b < B) {
            uint64_t tb = (uint64_t)(0xFFFFFFFFu - (uint32_t)ei);
            uint64_t k0 = ((uint64_t)f2mono(scores[node]) << 32) | tb;
            uint64_t k1 = ((uint64_t)f2mono(cosvals[node]) << 32) | tb;
            m0 = (k0 >= T[b]) ? 1.f : 0.f;
            m1 = (k1 >= T[B + b]) ? 1.f : 0.f;
        }
        uint64_t k2 = ((uint64_t)mx[node] << 32) | (uint64_t)(0xFFFFFFFFu - (uint32_t)node);
        float m2 = (k2 >= T[2 * B]) ? 1.f : 0.f;
        wm = w0 * m0 + w1 * m1 + w2 * m2;
    }
    size_t off = (size_t)node * DD + sub * 4;
    float4 h4 = *(const float4*)(hidden + off);
    float4 g4 = *(const float4*)(h0 + off);
    float4 o1, o2;
    o1.x = h4.x * wm; o1.y = h4.y * wm; o1.z = h4.z * wm; o1.w = h4.w * wm;
    o2.x = g4.x * wm; o2.y = g4.y * wm; o2.z = g4.z * wm; o2.w = g4.w * wm;
    *(float4*)(out_hidden + off) = o1;
    *(float4*)(out_h0 + off) = o2;
    if (sub == 0) out_scores[node] = scores[node] * wm;
}

// ================= host launch =================

extern "C" void kernel_launch(void* const* d_in, const int* in_sizes, int n_in,
                              void* d_out, int out_size, void* d_ws, size_t ws_size,
                              hipStream_t stream) {
    const float* hidden     = (const float*)d_in[0];
    const int*   nodes      = (const int*)d_in[1];
    const float* scores     = (const float*)d_in[2];
    const float* h0         = (const float*)d_in[3];
    const float* hidden_q   = (const float*)d_in[5];
    const int*   q_rel      = (const int*)d_in[6];
    const int*   edges      = (const int*)d_in[7];
    const int*   old_idx    = (const int*)d_in[8];
    const float* alpha_temp = (const float*)d_in[12];
    const int*   l_ptr      = (const int*)d_in[13];
    const float* noise      = (const float*)d_in[14];
    const float* mw1        = (const float*)d_in[15];
    const float* mb1        = (const float*)d_in[16];
    const float* mw2        = (const float*)d_in[17];
    const float* mb2        = (const float*)d_in[18];
    const float* rel_embed  = (const float*)d_in[19];
    const float* expert_emb = (const float*)d_in[20];
    const float* w_n        = (const float*)d_in[21];

    int N     = in_sizes[2];
    int NE    = in_sizes[12];
    int n_old = in_sizes[8];
    int B     = in_sizes[5] / DD;
    int CAP   = N / B;
    int nsel  = 2 * B + 1;

    size_t off = 0;
    auto take = [&](size_t bytes) -> size_t {
        size_t p = off; off += (bytes + 15) & ~(size_t)15; return p;
    };
    char* wsb = (char*)d_ws;
    float*    cosvals  = (float*)   (wsb + take((size_t)N * 4));
    uint32_t* mx       = (uint32_t*)(wsb + take((size_t)N * 4));
    uint8_t*  diff     = (uint8_t*) (wsb + take((size_t)N));
    int*      cnt      = (int*)     (wsb + take((size_t)B * 4));
    double*   partials = (double*)  (wsb + take((size_t)NWB * 4 * 8));
    int*      Kp       = (int*)     (wsb + take(16));
    int*      node_cnt = (int*)     (wsb + take(16));
    float*    escore   = (float*)   (wsb + take((size_t)B * 3 * 4));
    float*    nscale   = (float*)   (wsb + take((size_t)B * 4));
    float*    qvec     = (float*)   (wsb + take((size_t)B * DD * 4));
    float*    qnorm    = (float*)   (wsb + take((size_t)B * 4));
    float*    wvec     = (float*)   (wsb + take(16));
    uint64_t* T        = (uint64_t*)(wsb + take((size_t)nsel * 8));
    uint32_t* ghist    = (uint32_t*)(wsb + take((size_t)NBINS * 4));
    uint64_t* gcand    = (uint64_t*)(wsb + take((size_t)CAPG * 8));
    int*      gccnt    = (int*)     (wsb + take(16));
    uint32_t* g_state  = (uint32_t*)(wsb + take(16));
    size_t keys_bytes  = (size_t)B * CAP * 8;
    size_t nkeys_bytes = (size_t)N * 8;
    uint64_t *keys0, *keys1, *nkeys;
    if (ws_size >= off + 2 * keys_bytes + nkeys_bytes) {
        keys0 = (uint64_t*)(wsb + take(keys_bytes));
        keys1 = (uint64_t*)(wsb + take(keys_bytes));
        nkeys = (uint64_t*)(wsb + take(nkeys_bytes));
    } else {
        keys0 = (uint64_t*)d_out;                 // staged in d_out, read before final writes
        keys1 = keys0 + (size_t)B * CAP;
        nkeys = keys1 + (size_t)B * CAP;
    }

    float* out_hidden = (float*)d_out;
    float* out_scores = out_hidden + (size_t)N * DD;
    float* out_h0     = out_scores + N;
    float* out_L      = out_h0 + (size_t)N * DD;

    FusedParams fp;
    fp.hidden = hidden; fp.scores = scores; fp.h0 = h0; fp.hidden_q = hidden_q;
    fp.alpha_temp = alpha_temp; fp.noise = noise;
    fp.mw1 = mw1; fp.mb1 = mb1; fp.mw2 = mw2; fp.mb2 = mb2;
    fp.rel_embed = rel_embed; fp.expert_emb = expert_emb; fp.w_n = w_n;
    fp.nodes = nodes; fp.q_rel = q_rel; fp.edges = edges; fp.old_idx = old_idx; fp.l_ptr = l_ptr;
    fp.cosvals = cosvals; fp.mx = mx; fp.diff = diff; fp.cnt = cnt; fp.partials = partials;
    fp.Kp = Kp; fp.node_cnt = node_cnt; fp.escore = escore; fp.nscale = nscale;
    fp.qvec = qvec; fp.qnorm = qnorm; fp.wvec = wvec;
    fp.T = T; fp.ghist = ghist; fp.gcand = gcand; fp.gccnt = gccnt; fp.g_state = g_state;
    fp.keys0 = keys0; fp.keys1 = keys1; fp.nkeys = nkeys;
    fp.out_hidden = out_hidden; fp.out_scores = out_scores; fp.out_h0 = out_h0; fp.out_L = out_L;
    fp.N = N; fp.NE = NE; fp.n_old = n_old; fp.B = B; fp.CAP = CAP;

    void* kargs[] = { (void*)&fp };
    hipError_t rc = hipLaunchCooperativeKernel(fused_kernel, dim3(GBLK), dim3(256),
                                               kargs, 0, stream);
    if (rc == hipSuccess) return;
    (void)hipGetLastError();   // clear, fall back to multi-kernel pipeline

    int nb = (N + 255) / 256;
    init_kernel<<<nb, 256, 0, stream>>>(mx, diff, cnt, Kp, node_cnt, ghist, l_ptr, N, B);
    diff_kernel<<<(n_old + 255) / 256, 256, 0, stream>>>(diff, old_idx, n_old, N);
    ctx_kernel<<<B, 64, 0, stream>>>(hidden_q, q_rel, rel_embed, mw1, mb1, mw2, mb2,
                                     expert_emb, w_n, escore, nscale, qvec, qnorm, B);
    segmax_kernel<<<(NE + 255) / 256, 256, 0, stream>>>(edges, alpha_temp, mx, NE, N);
    nodewc_kernel<<<NWB, 256, 0, stream>>>(hidden, nodes, noise, qvec, qnorm,
                                           escore, nscale, cosvals, partials, N, B);
    stats_kernel<<<1, 256, 0, stream>>>(partials, wvec, out_L, N);
    compact_kernel<<<nb, 256, 0, stream>>>(nodes, diff, scores, cosvals, mx,
                                           keys0, keys1, nkeys, cnt, node_cnt, N, B, CAP);
    selA_kernel<<<2 * B + NHB, 1024, 0, stream>>>(keys0, keys1, cnt, nkeys, node_cnt,
                                                  ghist, T, Kp, B, CAP);
    selB_kernel<<<1, 1024, 0, stream>>>(nkeys, node_cnt, ghist, T, Kp, B);
    final_kernel<<<(N + 15) / 16, 256, 0, stream>>>(hidden, h0, scores, nodes, diff, cosvals,
                                                    mx, T, wvec, out_hidden, out_scores, out_h0, N, B);
}

// Round 4
// 823.362 us; speedup vs baseline: 2.0980x; 2.0980x over previous
//
#include <hip/hip_runtime.h>
#include <stdint.h>
#include <math.h>

#define DD 64
#define K_SOURCE_C 100
#define K_MIN_C 50
#define K_MAX_C 1000
#define L_INFL_C 4
#define A_SLOPE_C 1.0
#define COS_EPS_C 1e-8f
#define NBINS 8192
#define CAPC 3584
#define NHB 192
#define NWB 1024   // fixed grid for nodewc partials

__device__ __forceinline__ uint32_t f2mono(float f) {
    uint32_t u = __float_as_uint(f);
    return (u & 0x80000000u) ? ~u : (u | 0x80000000u);
}

__constant__ int c_shifts[5] = {51, 38, 25, 12, 0};
__constant__ int c_nbits[5]  = {13, 13, 13, 13, 12};

// ---- K1: init (blocks < nb) + ctx MLP (blocks nb..nb+B) — independent roles ----
__global__ void initctx_kernel(uint32_t* mx, uint8_t* diff, int* cnt,
                               int* Kp, int* node_cnt, uint32_t* ghist, const int* l_ptr,
                               const float* hidden_q, const int* q_rel, const float* rel_embed,
                               const float* w1, const float* b1, const float* w2, const float* b2,
                               const float* expert_emb, const float* w_n,
                               float* escore, float* nscale, float* qvec, float* qnorm,
                               int N, int B, int nb) {
    int blk = blockIdx.x, t = threadIdx.x;
    if (blk < nb) {
        int i = blk * 256 + t;
        if (i < N) { mx[i] = 0u; diff[i] = 1; }
        if (i < B) cnt[i] = 0;
        if (i < NBINS) ghist[i] = 0u;
        if (i == 0) {
            *node_cnt = 0;
            double l = (double)(*l_ptr);
            int K;
            if (l < (double)L_INFL_C) {
                double s = 1.0 / (1.0 + exp(-A_SLOPE_C * (l - L_INFL_C / 2.0)));
                K = (int)(K_SOURCE_C + (K_MAX_C - K_SOURCE_C) * s);
            } else {
                double s = 1.0 / (1.0 + exp(-A_SLOPE_C * (l - 3.0 * L_INFL_C / 2.0)));
                K = (int)(K_MIN_C + (K_MAX_C - K_MIN_C) * (1.0 - s));
            }
            *Kp = K;
        }
        return;
    }
    // ctx role: one block per batch row, threads 0..63 active
    int b = blk - nb;
    if (b >= B) return;
    __shared__ float cin[2 * DD];
    __shared__ float h1s[DD];
    float qv = 0.f;
    if (t < DD) {
        int q = q_rel[b];
        qv = rel_embed[(size_t)q * DD + t];
        qvec[b * DD + t] = qv;
        cin[t] = hidden_q[b * DD + t];
        cin[DD + t] = qv;
    }
    __syncthreads();
    if (t < DD) {
        float acc = b1[t];
        for (int j = 0; j < 2 * DD; j++) acc += cin[j] * w1[j * DD + t];
        h1s[t] = fmaxf(acc, 0.f);
    }
    __syncthreads();
    if (t < DD) {
        float c = b2[t];
        for (int j = 0; j < DD; j++) c += h1s[j] * w2[j * DD + t];
        float e0 = c * expert_emb[0 * DD + t];
        float e1 = c * expert_emb[1 * DD + t];
        float e2 = c * expert_emb[2 * DD + t];
        float wn = c * w_n[t];
        float qq = qv * qv;
        for (int m = 32; m >= 1; m >>= 1) {
            e0 += __shfl_xor(e0, m); e1 += __shfl_xor(e1, m); e2 += __shfl_xor(e2, m);
            wn += __shfl_xor(wn, m); qq += __shfl_xor(qq, m);
        }
        if (t == 0) {
            escore[b * 3 + 0] = e0; escore[b * 3 + 1] = e1; escore[b * 3 + 2] = e2;
            nscale[b] = fmaxf(wn, 0.f) + log1pf(expf(-fabsf(wn)));   // stable softplus
            qnorm[b] = fmaxf(sqrtf(qq), COS_EPS_C);
        }
    }
}

// ---- K2: segment max (blocks < eb) + diff clears (blocks >= eb) — independent ----
__global__ void segdiff_kernel(const int* edges, const float* alpha_temp, uint32_t* mx,
                               uint8_t* diff, const int* old_idx,
                               int NE, int n_old, int N, int eb) {
    int blk = blockIdx.x, t = threadIdx.x;
    if (blk < eb) {
        int e = blk * 256 + t;
        if (e < NE) {
            int o = edges[(size_t)e * 6 + 5];
            if (o >= 0 && o < N) atomicMax(&mx[o], f2mono(alpha_temp[e]));
        }
    } else {
        int j = (blk - eb) * 256 + t;
        if (j < n_old) {
            int idx = old_idx[j];
            if (idx >= 0 && idx < N) diff[idx] = 0;
        }
    }
}

// ---- K3: fused per-node pass: cosine (16 lanes/node) + expert weight partials ----
// Fixed grid + register accumulation + per-block partials store.
// (NO same-address global atomics — 128K hot-address f64 atomicAdds serialized
//  at ~17ns each = 2.2ms in the round-1 version.)
__global__ void nodewc_kernel(const float* hidden, const int* nodes, const float* noise,
                              const float* qvec, const float* qnorm,
                              const float* escore, const float* nscale,
                              float* cosvals, double* partials, int N, int B) {
    int t = threadIdx.x;                    // 256 threads = 16 nodes per group
    int sub = t & 15;
    double s0 = 0, s1 = 0, s2 = 0, sq = 0;
    int ngroups = (N + 15) >> 4;
    for (int g = blockIdx.x; g < ngroups; g += gridDim.x) {
        int node = g * 16 + (t >> 4);
        if (node < N) {
            int b = nodes[2 * node];
            bool bv = (b >= 0 && b < B);
            float4 h4 = *(const float4*)(hidden + (size_t)node * DD + sub * 4);
            float num = 0.f;
            if (bv) {
                float4 q4 = *(const float4*)(qvec + b * DD + sub * 4);
                num = h4.x * q4.x + h4.y * q4.y + h4.z * q4.z + h4.w * q4.w;
            }
            float hs = h4.x * h4.x + h4.y * h4.y + h4.z * h4.z + h4.w * h4.w;
            for (int m = 8; m >= 1; m >>= 1) { num += __shfl_xor(num, m); hs += __shfl_xor(hs, m); }
            if (sub == 0) {
                float qn = bv ? qnorm[b] : COS_EPS_C;
                cosvals[node] = num / (fmaxf(sqrtf(hs), COS_EPS_C) * qn);
                if (bv) {
                    float ns = nscale[b];
                    float e0 = escore[b * 3 + 0] + noise[3 * node + 0] * ns;
                    float e1 = escore[b * 3 + 1] + noise[3 * node + 1] * ns;
                    float e2 = escore[b * 3 + 2] + noise[3 * node + 2] * ns;
                    float mm = fmaxf(e0, fmaxf(e1, e2));
                    float x0 = expf(e0 - mm), x1 = expf(e1 - mm), x2 = expf(e2 - mm);
                    float s = x0 + x1 + x2;
                    x0 /= s; x1 /= s; x2 /= s;
                    s0 += x0; s1 += x1; s2 += x2;
                    sq += (double)x0 * x0 + (double)x1 * x1 + (double)x2 * x2;
                }
            }
        }
    }
    for (int m = 32; m >= 1; m >>= 1) {
        s0 += __shfl_xor(s0, m); s1 += __shfl_xor(s1, m);
        s2 += __shfl_xor(s2, m); sq += __shfl_xor(sq, m);
    }
    __shared__ double red[4][4];
    int wid = t >> 6, lane = t & 63;
    if (lane == 0) { red[wid][0] = s0; red[wid][1] = s1; red[wid][2] = s2; red[wid][3] = sq; }
    __syncthreads();
    if (t == 0) {
        double a0 = 0, a1 = 0, a2 = 0, a3 = 0;
        for (int w = 0; w < 4; w++) { a0 += red[w][0]; a1 += red[w][1]; a2 += red[w][2]; a3 += red[w][3]; }
        partials[blockIdx.x * 4 + 0] = a0;
        partials[blockIdx.x * 4 + 1] = a1;
        partials[blockIdx.x * 4 + 2] = a2;
        partials[blockIdx.x * 4 + 3] = a3;
    }
}

// ---- K4: compact (blocks < nb) + stats reduction (block nb) — independent ----
__global__ void compactstats_kernel(const int* nodes, const uint8_t* diff, const float* scores,
                                    const float* cosvals, const uint32_t* mx,
                                    uint64_t* keys0, uint64_t* keys1, uint64_t* nkeys,
                                    int* cnt, int* node_cnt,
                                    const double* partials, float* wvec, float* out_L,
                                    int N, int B, int CAP, int nb) {
    int blk = blockIdx.x, t = threadIdx.x;
    if (blk == nb) {
        // stats role: reduce partials -> wvec, L_imp
        double s0 = 0, s1 = 0, s2 = 0, sq = 0;
        for (int i = t; i < NWB; i += 256) {
            s0 += partials[4 * i + 0]; s1 += partials[4 * i + 1];
            s2 += partials[4 * i + 2]; sq += partials[4 * i + 3];
        }
        for (int m = 32; m >= 1; m >>= 1) {
            s0 += __shfl_xor(s0, m); s1 += __shfl_xor(s1, m);
            s2 += __shfl_xor(s2, m); sq += __shfl_xor(sq, m);
        }
        __shared__ double red[4][4];
        int wid = t >> 6, lane = t & 63;
        if (lane == 0) { red[wid][0] = s0; red[wid][1] = s1; red[wid][2] = s2; red[wid][3] = sq; }
        __syncthreads();
        if (t == 0) {
            double c0 = 0, c1 = 0, c2 = 0, S2 = 0;
            for (int w = 0; w < 4; w++) { c0 += red[w][0]; c1 += red[w][1]; c2 += red[w][2]; S2 += red[w][3]; }
            double tot = c0 + c1 + c2;
            wvec[0] = (float)(c0 / tot); wvec[1] = (float)(c1 / tot); wvec[2] = (float)(c2 / tot);
            double n = 3.0 * (double)N;
            double mean = tot / n;
            double var = (S2 - tot * tot / n) / (n - 1.0);   // ddof=1
            if (var < 0) var = 0;
            double cv = sqrt(var) / (mean + 1e-5);
            *out_L = (float)(cv * cv);
        }
        return;
    }
    __shared__ int lcnt[64];
    __shared__ int lbase[64];
    __shared__ int nloc_cnt, nloc_base;
    if (t < B) lcnt[t] = 0;
    if (t == 0) nloc_cnt = 0;
    __syncthreads();
    int i = blk * 256 + t;
    int b = -1, loc = 0, nl = 0;
    bool isdiff = (i < N) && diff[i];
    if (isdiff) {
        nl = atomicAdd(&nloc_cnt, 1);
        int bb = nodes[2 * i];
        if (bb >= 0 && bb < B) { b = bb; loc = atomicAdd(&lcnt[b], 1); }
    }
    __syncthreads();
    if (t < B) lbase[t] = lcnt[t] ? atomicAdd(&cnt[t], lcnt[t]) : 0;
    if (t == 0) nloc_base = nloc_cnt ? atomicAdd(node_cnt, nloc_cnt) : 0;
    __syncthreads();
    if (isdiff) {
        nkeys[nloc_base + nl] = ((uint64_t)mx[i] << 32) | (uint64_t)(0xFFFFFFFFu - (uint32_t)i);
        if (b >= 0) {
            int pos = lbase[b] + loc;
            if (pos < CAP) {
                int ei = nodes[2 * i + 1];
                uint64_t tb = (uint64_t)(0xFFFFFFFFu - (uint32_t)ei);
                keys0[(size_t)b * CAP + pos] = ((uint64_t)f2mono(scores[i]) << 32) | tb;
                keys1[(size_t)b * CAP + pos] = ((uint64_t)f2mono(cosvals[i]) << 32) | tb;
            }
        }
    }
}

// ---------------- block-wide pick over LDS histogram (1024 threads) ----------------
struct PickScratch { uint32_t wtot[16]; int fd; uint32_t fK; uint32_t total; };

__device__ void block_pick(const uint32_t* hist, int nbins, uint32_t Kr, PickScratch* sc) {
    int t = threadIdx.x;
    int PB = nbins >> 10;                 // bins per thread: 8 or 4
    int lane = t & 63, wid = t >> 6;
    uint32_t csum = 0;
    for (int j = 0; j < PB; j++) csum += hist[PB * t + j];
    uint32_t ssum = csum;                 // inclusive suffix within wave (desc. bins)
    for (int off = 1; off < 64; off <<= 1) {
        uint32_t v = __shfl_down(ssum, off, 64);
        if (lane + off < 64) ssum += v;
    }
    if (lane == 0) sc->wtot[wid] = ssum;
    if (t == 0) sc->fd = -1;
    __syncthreads();
    uint32_t above = 0, total = 0;
#pragma unroll
    for (int w = 0; w < 16; w++) {
        uint32_t v = sc->wtot[w];
        total += v;
        if (w > wid) above += v;
    }
    uint32_t gcnt = ssum + above - csum;  // strictly above this thread's chunk
    int fd = -1; uint32_t fK = 0;
    for (int j = PB - 1; j >= 0; j--) {
        uint32_t h = hist[PB * t + j];
        if (h && gcnt < Kr && gcnt + h >= Kr) { fd = PB * t + j; fK = Kr - gcnt; }
        gcnt += h;
    }
    if (fd >= 0) { sc->fd = fd; sc->fK = fK; }
    if (t == 0) sc->total = total;
    __syncthreads();
}

// ---- K5: rows fully selected in-block; node level-0 histogram ----
__global__ __launch_bounds__(1024)
void selA_kernel(const uint64_t* keys0, const uint64_t* keys1, const int* cnt,
                 const uint64_t* nkeys, const int* node_cnt, uint32_t* ghist,
                 uint64_t* T, const int* Kp, int B, int CAP) {
    __shared__ uint32_t hist[NBINS];
    __shared__ PickScratch sc;
    int t = threadIdx.x;
    int blk = blockIdx.x;
    if (blk < 2 * B) {
        int row = (blk < B) ? blk : blk - B;
        const uint64_t* list = ((blk < B) ? keys0 : keys1) + (size_t)row * CAP;
        int n = min(cnt[row], CAP);
        int K = *Kp;
        if (n <= K) { if (t == 0) T[blk] = 0ull; return; }
        uint64_t pref = 0ull;
        uint32_t Kr = (uint32_t)K;
        for (int lev = 0; lev < 5; lev++) {
            int nb = 1 << c_nbits[lev];
            for (int j = t; j < nb; j += 1024) hist[j] = 0;
            __syncthreads();
            uint64_t pmask = (lev == 0) ? 0ull : (~0ull << c_shifts[lev - 1]);
            int sh = c_shifts[lev];
            uint32_t bmask = (uint32_t)(nb - 1);
            for (int i = t; i < n; i += 1024) {
                uint64_t key = list[i];
                if ((key & pmask) == pref)
                    atomicAdd(&hist[(uint32_t)(key >> sh) & bmask], 1u);
            }
            __syncthreads();
            block_pick(hist, nb, Kr, &sc);
            if (sc.fd < 0) { if (t == 0) T[blk] = 0ull; return; }  // structurally unreachable
            pref |= ((uint64_t)sc.fd) << sh;
            Kr = sc.fK;
            __syncthreads();
        }
        if (t == 0) T[blk] = pref;
    } else {
        int nb = blk - 2 * B;             // node-hist block id
        for (int j = t; j < NBINS; j += 1024) hist[j] = 0;
        __syncthreads();
        int n = *node_cnt;
        for (int i = nb * 1024 + t; i < n; i += NHB * 1024)
            atomicAdd(&hist[(uint32_t)(nkeys[i] >> 51)], 1u);
        __syncthreads();
        for (int j = t; j < NBINS; j += 1024) {
            uint32_t v = hist[j];
            if (v) atomicAdd(&ghist[j], v);
        }
    }
}

// ---- K6: node pick + collect + finish (1 block) ----
__global__ __launch_bounds__(1024)
void selB_kernel(const uint64_t* nkeys, const int* node_cnt, const uint32_t* ghist,
                 uint64_t* T, const int* Kp, int B) {
    __shared__ uint32_t hist[NBINS];
    __shared__ uint64_t cand[CAPC];
    __shared__ PickScratch sc;
    __shared__ int ccnt;
    int t = threadIdx.x;
    int K = *Kp;
    int n = *node_cnt;
    for (int j = t; j < NBINS; j += 1024) hist[j] = ghist[j];
    __syncthreads();
    block_pick(hist, NBINS, (uint32_t)K, &sc);
    if (sc.total <= (uint32_t)K || sc.fd < 0) { if (t == 0) T[2 * B] = 0ull; return; }
    int fd0 = sc.fd;
    uint64_t pref = ((uint64_t)fd0) << 51;
    uint32_t Kr = sc.fK;
    if (t == 0) ccnt = 0;
    __syncthreads();
    for (int i = t; i < n; i += 1024) {          // collect threshold-bin candidates
        uint64_t key = nkeys[i];
        if ((int)(key >> 51) == fd0) {
            int p = atomicAdd(&ccnt, 1);
            if (p < CAPC) cand[p] = key;
        }
    }
    __syncthreads();
    int m = ccnt;
    bool inlds = (m <= CAPC);                    // overflow -> global-stream fallback
    if (!inlds) m = n;
    for (int lev = 1; lev < 5; lev++) {
        int nb = 1 << c_nbits[lev];
        for (int j = t; j < nb; j += 1024) hist[j] = 0;
        __syncthreads();
        uint64_t pmask = ~0ull << c_shifts[lev - 1];
        int sh = c_shifts[lev];
        uint32_t bmask = (uint32_t)(nb - 1);
        for (int i = t; i < m; i += 1024) {
            uint64_t key = inlds ? cand[i] : nkeys[i];
            if ((key & pmask) == pref)
                atomicAdd(&hist[(uint32_t)(key >> sh) & bmask], 1u);
        }
        __syncthreads();
        block_pick(hist, nb, Kr, &sc);
        if (sc.fd < 0) { if (t == 0) T[2 * B] = 0ull; return; }  // structurally unreachable
        pref |= ((uint64_t)sc.fd) << sh;
        Kr = sc.fK;
        __syncthreads();
    }
    if (t == 0) T[2 * B] = pref;
}

// ---- K7: fused epilogue; wm computed once per node, shfl-broadcast to 16 lanes ----
__global__ void final_kernel(const float* hidden, const float* h0, const float* scores,
                             const int* nodes, const uint8_t* diff, const float* cosvals,
                             const uint32_t* mx, const uint64_t* T, const float* wvec,
                             float* out_hidden, float* out_scores, float* out_h0,
                             int N, int B) {
    int t = threadIdx.x;
    int node = blockIdx.x * 16 + (t >> 4);
    int sub = t & 15;
    bool ok = node < N;
    float wm = 0.f;
    float sc0 = 0.f;
    if (ok && sub == 0) {
        float w0 = wvec[0], w1 = wvec[1], w2 = wvec[2];
        sc0 = scores[node];
        if (!diff[node]) {
            wm = w0 + w1 + w2;
        } else {
            int b = nodes[2 * node];
            int ei = nodes[2 * node + 1];
            float m0 = 0.f, m1 = 0.f;
            if (b >= 0 && b < B) {
                uint64_t tb = (uint64_t)(0xFFFFFFFFu - (uint32_t)ei);
                uint64_t k0 = ((uint64_t)f2mono(sc0) << 32) | tb;
                uint64_t k1 = ((uint64_t)f2mono(cosvals[node]) << 32) | tb;
                m0 = (k0 >= T[b]) ? 1.f : 0.f;
                m1 = (k1 >= T[B + b]) ? 1.f : 0.f;
            }
            uint64_t k2 = ((uint64_t)mx[node] << 32) | (uint64_t)(0xFFFFFFFFu - (uint32_t)node);
            float m2 = (k2 >= T[2 * B]) ? 1.f : 0.f;
            wm = w0 * m0 + w1 * m1 + w2 * m2;
        }
    }
    wm = __shfl(wm, (t & 63) & ~15, 64);     // broadcast from sub==0 within 16-lane group
    if (!ok) return;
    size_t off = (size_t)node * DD + sub * 4;
    float4 h4 = *(const float4*)(hidden + off);
    float4 g4 = *(const float4*)(h0 + off);
    float4 o1, o2;
    o1.x = h4.x * wm; o1.y = h4.y * wm; o1.z = h4.z * wm; o1.w = h4.w * wm;
    o2.x = g4.x * wm; o2.y = g4.y * wm; o2.z = g4.z * wm; o2.w = g4.w * wm;
    *(float4*)(out_hidden + off) = o1;
    *(float4*)(out_h0 + off) = o2;
    if (sub == 0) out_scores[node] = sc0 * wm;
}

extern "C" void kernel_launch(void* const* d_in, const int* in_sizes, int n_in,
                              void* d_out, int out_size, void* d_ws, size_t ws_size,
                              hipStream_t stream) {
    const float* hidden     = (const float*)d_in[0];
    const int*   nodes      = (const int*)d_in[1];
    const float* scores     = (const float*)d_in[2];
    const float* h0         = (const float*)d_in[3];
    const float* hidden_q   = (const float*)d_in[5];
    const int*   q_rel      = (const int*)d_in[6];
    const int*   edges      = (const int*)d_in[7];
    const int*   old_idx    = (const int*)d_in[8];
    const float* alpha_temp = (const float*)d_in[12];
    const int*   l_ptr      = (const int*)d_in[13];
    const float* noise      = (const float*)d_in[14];
    const float* mw1        = (const float*)d_in[15];
    const float* mb1        = (const float*)d_in[16];
    const float* mw2        = (const float*)d_in[17];
    const float* mb2        = (const float*)d_in[18];
    const float* rel_embed  = (const float*)d_in[19];
    const float* expert_emb = (const float*)d_in[20];
    const float* w_n        = (const float*)d_in[21];

    int N     = in_sizes[2];
    int NE    = in_sizes[12];
    int n_old = in_sizes[8];
    int B     = in_sizes[5] / DD;
    int CAP   = N / B;
    int nsel  = 2 * B + 1;

    size_t off = 0;
    auto take = [&](size_t bytes) -> size_t {
        size_t p = off; off += (bytes + 15) & ~(size_t)15; return p;
    };
    char* wsb = (char*)d_ws;
    float*    cosvals  = (float*)   (wsb + take((size_t)N * 4));
    uint32_t* mx       = (uint32_t*)(wsb + take((size_t)N * 4));
    uint8_t*  diff     = (uint8_t*) (wsb + take((size_t)N));
    int*      cnt      = (int*)     (wsb + take((size_t)B * 4));
    double*   partials = (double*)  (wsb + take((size_t)NWB * 4 * 8));
    int*      Kp       = (int*)     (wsb + take(16));
    int*      node_cnt = (int*)     (wsb + take(16));
    float*    escore   = (float*)   (wsb + take((size_t)B * 3 * 4));
    float*    nscale   = (float*)   (wsb + take((size_t)B * 4));
    float*    qvec     = (float*)   (wsb + take((size_t)B * DD * 4));
    float*    qnorm    = (float*)   (wsb + take((size_t)B * 4));
    float*    wvec     = (float*)   (wsb + take(16));
    uint64_t* T        = (uint64_t*)(wsb + take((size_t)nsel * 8));
    uint32_t* ghist    = (uint32_t*)(wsb + take((size_t)NBINS * 4));
    size_t keys_bytes  = (size_t)B * CAP * 8;
    size_t nkeys_bytes = (size_t)N * 8;
    uint64_t *keys0, *keys1, *nkeys;
    if (ws_size >= off + 2 * keys_bytes + nkeys_bytes) {
        keys0 = (uint64_t*)(wsb + take(keys_bytes));
        keys1 = (uint64_t*)(wsb + take(keys_bytes));
        nkeys = (uint64_t*)(wsb + take(nkeys_bytes));
    } else {
        // stage keys in d_out (written by compact, read by selA/selB, overwritten by final)
        keys0 = (uint64_t*)d_out;
        keys1 = keys0 + (size_t)B * CAP;
        nkeys = keys1 + (size_t)B * CAP;
    }

    float* out_hidden = (float*)d_out;
    float* out_scores = out_hidden + (size_t)N * DD;
    float* out_h0     = out_scores + N;
    float* out_L      = out_h0 + (size_t)N * DD;

    int nb = (N + 255) / 256;
    int eb = (NE + 255) / 256;
    int ob = (n_old + 255) / 256;

    initctx_kernel<<<nb + B, 256, 0, stream>>>(mx, diff, cnt, Kp, node_cnt, ghist, l_ptr,
                                               hidden_q, q_rel, rel_embed, mw1, mb1, mw2, mb2,
                                               expert_emb, w_n, escore, nscale, qvec, qnorm,
                                               N, B, nb);
    segdiff_kernel<<<eb + ob, 256, 0, stream>>>(edges, alpha_temp, mx, diff, old_idx,
                                                NE, n_old, N, eb);
    nodewc_kernel<<<NWB, 256, 0, stream>>>(hidden, nodes, noise, qvec, qnorm,
                                           escore, nscale, cosvals, partials, N, B);
    compactstats_kernel<<<nb + 1, 256, 0, stream>>>(nodes, diff, scores, cosvals, mx,
                                                    keys0, keys1, nkeys, cnt, node_cnt,
                                                    partials, wvec, out_L, N, B, CAP, nb);
    selA_kernel<<<2 * B + NHB, 1024, 0, stream>>>(keys0, keys1, cnt, nkeys, node_cnt,
                                                  ghist, T, Kp, B, CAP);
    selB_kernel<<<1, 1024, 0, stream>>>(nkeys, node_cnt, ghist, T, Kp, B);
    final_kernel<<<(N + 15) / 16, 256, 0, stream>>>(hidden, h0, scores, nodes, diff, cosvals,
                                                    mx, T, wvec, out_hidden, out_scores, out_h0, N, B);
}